// Round 5
// baseline (98.643 us; speedup 1.0000x reference)
//
#include <hip/hip_runtime.h>
#include <hip/hip_bf16.h>

// Qu mutual-information circuit: N_QUBITS=12, DIM=4096, SUB_DIM=64, 1 layer.
//
// Full reduction (see round-3 notes; all formulas verified by passing bench):
//   L = LA (x) LB,  U = L P L,  Tr_B(U (X1(x)X2) U^H) = LA * T * LA^H
//   P GF(2)-linear => T[p,q] = A1[u,v]*W0(p0,q0) + A1[u^48,v^48]*W1(p0,q0),
//     u = p^(p>>1), v = q^(q>>1) (Gray code), coefficients from 4 scalars
//     e0,e1,f0,f1 = parity-split operator traces of the LB side (LB GEMMs
//     eliminated entirely via unitarity).
//
// ONE kernel, 16 blocks x 1024 threads = (evolution 0..3) x (row-quarter 0..3).
// Each block redundantly computes A1 + traces + T for its evolution (CUs are
// idle anyway), then writes only its 16-row quarter of OUT = LA*T*LA^H.
// No workspace, one dispatch.

#define W_MUL 0.6324555320336759f   // sqrt(2)/sqrt(5)

__device__ __forceinline__ float2 cmul(float2 a, float2 b) {
    return make_float2(a.x * b.x - a.y * b.y, a.x * b.y + a.y * b.x);
}
__device__ __forceinline__ float2 cadd(float2 a, float2 b) { return make_float2(a.x + b.x, a.y + b.y); }
__device__ __forceinline__ float2 csub(float2 a, float2 b) { return make_float2(a.x - b.x, a.y - b.y); }
__device__ __forceinline__ float2 conjc(float2 a) { return make_float2(a.x, -a.y); }
// c += a*b
__device__ __forceinline__ float2 cfma(float2 a, float2 b, float2 c) {
    c.x = fmaf(a.x, b.x, fmaf(-a.y, b.y, c.x));
    c.y = fmaf(a.x, b.y, fmaf( a.y, b.x, c.y));
    return c;
}
// c += conj(a)*b
__device__ __forceinline__ float2 cfmac(float2 a, float2 b, float2 c) {
    c.x = fmaf(a.x, b.x, fmaf( a.y, b.y, c.x));
    c.y = fmaf(a.x, b.y, fmaf(-a.y, b.x, c.y));
    return c;
}

// G_q = Rz(tz) @ Ry(ty) @ Rx(tx), 2x2 complex.
__device__ __forceinline__ void make_G(const float* w, int q, float2 G[2][2]) {
    float tx = w[q]      * (W_MUL * 0.5f);
    float ty = w[12 + q] * (W_MUL * 0.5f);
    float tz = w[24 + q] * (W_MUL * 0.5f);
    float cx, sx, cy, sy, cz, sz;
    sincosf(tx, &sx, &cx);
    sincosf(ty, &sy, &cy);
    sincosf(tz, &sz, &cz);
    float2 M00 = make_float2( cy * cx,  sy * sx);
    float2 M01 = make_float2(-sy * cx, -cy * sx);
    float2 M10 = make_float2( sy * cx, -cy * sx);
    float2 M11 = make_float2( cy * cx, -sy * sx);
    float2 ez  = make_float2(cz, -sz);
    float2 ezc = make_float2(cz,  sz);
    G[0][0] = cmul(ez,  M00);
    G[0][1] = cmul(ez,  M01);
    G[1][0] = cmul(ezc, M10);
    G[1][1] = cmul(ezc, M11);
}

// dst[k*64+i] = conj(L[i][k]) for L = kron(G[0..5]).
__device__ __forceinline__ void build_LH(const float2 G[6][2][2], float2* dst, int t, int nt) {
    for (int e = t; e < 4096; e += nt) {
        int i = e >> 6, j = e & 63;
        float2 p = G[0][(i >> 5) & 1][(j >> 5) & 1];
        p = cmul(p, G[1][(i >> 4) & 1][(j >> 4) & 1]);
        p = cmul(p, G[2][(i >> 3) & 1][(j >> 3) & 1]);
        p = cmul(p, G[3][(i >> 2) & 1][(j >> 2) & 1]);
        p = cmul(p, G[4][(i >> 1) & 1][(j >> 1) & 1]);
        p = cmul(p, G[5][(i     ) & 1][(j     ) & 1]);
        dst[j * 64 + i] = conjc(p);
    }
}

// 2x2 trace tables from G (qubits 6..11): zt[q] = Gq^H Z Gq; x6 = G6^H X G6; xz6 = G6^H (XZ) G6.
__device__ __forceinline__ void make_tables(const float2 G[6][2][2],
                                            float2 zt[6][2][2], float2 x6[2][2], float2 xz6[2][2]) {
    #pragma unroll
    for (int q = 0; q < 6; ++q)
        #pragma unroll
        for (int a = 0; a < 2; ++a)
            #pragma unroll
            for (int b = 0; b < 2; ++b) {
                float2 g0a = G[q][0][a], g0b = G[q][0][b];
                float2 g1a = G[q][1][a], g1b = G[q][1][b];
                zt[q][a][b] = csub(cmul(conjc(g0a), g0b), cmul(conjc(g1a), g1b));
                if (q == 0) {
                    x6[a][b]  = cadd(cmul(conjc(g0a), g1b), cmul(conjc(g1a), g0b));
                    xz6[a][b] = csub(cmul(conjc(g1a), g0b), cmul(conjc(g0a), g1b));
                }
            }
}

// Per-thread trace partials: acc = {tz.x,tz.y, txz.x,txz.y, tx.x,tx.y, t0}
__device__ __forceinline__ void trace_acc(const float* Xr, const float2 zt[6][2][2],
                                          const float2 x6[2][2], const float2 xz6[2][2],
                                          int t, int nt, float acc[7]) {
    for (int e = t; e < 4096; e += nt) {
        int r = e >> 6, c = e & 63;       // term X2[r][c] * K[c][r]
        float xv = Xr[e];
        float2 P = zt[1][(c >> 4) & 1][(r >> 4) & 1];
        P = cmul(P, zt[2][(c >> 3) & 1][(r >> 3) & 1]);
        P = cmul(P, zt[3][(c >> 2) & 1][(r >> 2) & 1]);
        P = cmul(P, zt[4][(c >> 1) & 1][(r >> 1) & 1]);
        P = cmul(P, zt[5][c & 1][r & 1]);
        float2 pz  = cmul(zt[0][c >> 5][r >> 5], P);
        float2 pxz = cmul(xz6[c >> 5][r >> 5], P);
        acc[0] = fmaf(pz.x,  xv, acc[0]); acc[1] = fmaf(pz.y,  xv, acc[1]);
        acc[2] = fmaf(pxz.x, xv, acc[2]); acc[3] = fmaf(pxz.y, xv, acc[3]);
        if ((c & 31) == (r & 31)) {
            float2 kx = x6[c >> 5][r >> 5];
            acc[4] = fmaf(kx.x, xv, acc[4]); acc[5] = fmaf(kx.y, xv, acc[5]);
            if (c == r) acc[6] += xv;
        }
    }
}

// Reduce acc[7] across the block; returns true on thread 0 with totals in acc.
template <int NT>
__device__ __forceinline__ bool reduce7(float acc[7], float (*red)[8], int t) {
    #pragma unroll
    for (int o = 32; o; o >>= 1)
        #pragma unroll
        for (int m = 0; m < 7; ++m) acc[m] += __shfl_down(acc[m], o);
    if ((t & 63) == 0)
        for (int m = 0; m < 7; ++m) red[t >> 6][m] = acc[m];
    __syncthreads();
    if (t == 0) {
        for (int m = 0; m < 7; ++m) {
            float s = 0.f;
            for (int wv = 0; wv < NT / 64; ++wv) s += red[wv][m];
            acc[m] = s;
        }
        return true;
    }
    return false;
}

// T coefficients by (p&1, q&1)
__device__ __forceinline__ void pick_cc(int p, int q, float2 e0, float2 e1, float2 f0, float2 f1,
                                        float2& c0, float2& c1) {
    if (p & 1) { if (q & 1) { c0 = e1; c1 = e0; } else { c0 = f1; c1 = f0; } }
    else       { if (q & 1) { c0 = f0; c1 = f1; } else { c0 = e0; c1 = e1; } }
}

// ---------------- Fused kernel: 16 blocks x 1024 = (evolution) x (row-quarter) ----------------
// OM: 0 = f32 real-only, 1 = bf16 interleaved, 2 = f32 interleaved
template <int OM>
__global__ __launch_bounds__(1024) void qfused(const float* __restrict__ A, const float* __restrict__ B,
                                               const float* __restrict__ w, void* __restrict__ outv) {
    __shared__ float2 LAH[4096];    // conj-transpose of LA (stable all kernel)
    __shared__ float  Xr[4096];     // X1 then X2
    __shared__ float2 BA[4096];     // TMP -> T
    __shared__ float2 BB[4096];     // A1 -> U
    __shared__ float2 G6[6][2][2];
    __shared__ float  red[16][8];
    __shared__ float2 Sq[4];

    const int bx = blockIdx.x;
    const int ev = bx >> 2, rq = bx & 3;
    const int order = ev >> 1, b = ev & 1;
    const int t = threadIdx.x;
    const float* X1g = (order ? B : A) + b * 4096;   // LA-side factor (retained)
    const float* X2g = (order ? A : B) + b * 4096;   // LB-side factor (traced out)

    // ---- Phase 1: G(0..5) -> G6; LAH; X1 -> Xr ----
    if (t < 6) make_G(w, t, G6[t]);
    __syncthreads();
    build_LH(G6, LAH, t, 1024);
    for (int e = t; e < 4096; e += 1024) Xr[e] = X1g[e];
    __syncthreads();

    const int tr = t >> 5, tc = t & 31;
    const int i0 = tr, i1 = tr + 32;

    // ---- Phase 2: GEMM1: BA = LA @ X1  (LA[i][k] = conj(LAH[k*64+i]), X real) ----
    {
        float2 a00 = {0,0}, a01 = {0,0}, a10 = {0,0}, a11 = {0,0};
        #pragma unroll 16
        for (int k = 0; k < 64; ++k) {
            float2 la0 = LAH[(k << 6) + i0], la1 = LAH[(k << 6) + i1];
            float x0 = Xr[(k << 6) + tc], x1 = Xr[(k << 6) + tc + 32];
            a00.x = fmaf(la0.x, x0, a00.x); a00.y = fmaf(-la0.y, x0, a00.y);
            a01.x = fmaf(la0.x, x1, a01.x); a01.y = fmaf(-la0.y, x1, a01.y);
            a10.x = fmaf(la1.x, x0, a10.x); a10.y = fmaf(-la1.y, x0, a10.y);
            a11.x = fmaf(la1.x, x1, a11.x); a11.y = fmaf(-la1.y, x1, a11.y);
        }
        BA[(i0 << 6) + tc] = a00; BA[(i0 << 6) + tc + 32] = a01;
        BA[(i1 << 6) + tc] = a10; BA[(i1 << 6) + tc + 32] = a11;
    }
    __syncthreads();

    // ---- Phase 3: GEMM2: BB = A1 = BA @ LA^H  (A1[i][j] = sum_k BA[i][k]*LAH[k*64+j]) ----
    {
        float2 a00 = {0,0}, a01 = {0,0}, a10 = {0,0}, a11 = {0,0};
        #pragma unroll 16
        for (int k = 0; k < 64; ++k) {
            float2 t0 = BA[(i0 << 6) + k], t1 = BA[(i1 << 6) + k];
            float2 l0 = LAH[(k << 6) + tc], l1 = LAH[(k << 6) + tc + 32];
            a00 = cfma(t0, l0, a00); a01 = cfma(t0, l1, a01);
            a10 = cfma(t1, l0, a10); a11 = cfma(t1, l1, a11);
        }
        BB[(i0 << 6) + tc] = a00; BB[(i0 << 6) + tc + 32] = a01;
        BB[(i1 << 6) + tc] = a10; BB[(i1 << 6) + tc + 32] = a11;
    }
    __syncthreads();

    // ---- Phase 4: X2 -> Xr; G(6..11) -> G6; traces -> Sq ----
    // (Xr last read in phase 2, G6 last read in phase 1 — both behind syncs.)
    for (int e = t; e < 4096; e += 1024) Xr[e] = X2g[e];
    if (t < 6) make_G(w, 6 + t, G6[t]);
    __syncthreads();
    {
        float2 zt[6][2][2], x6[2][2], xz6[2][2];
        make_tables(G6, zt, x6, xz6);
        float acc[7] = {0, 0, 0, 0, 0, 0, 0};
        trace_acc(Xr, zt, x6, xz6, t, 1024, acc);
        if (reduce7<1024>(acc, red, t)) {
            Sq[0] = make_float2(0.5f * (acc[6] + acc[0]),  0.5f * acc[1]);              // e0
            Sq[1] = make_float2(0.5f * (acc[6] - acc[0]), -0.5f * acc[1]);              // e1
            Sq[2] = make_float2(0.5f * (acc[4] + acc[2]),  0.5f * (acc[5] + acc[3]));   // f0
            Sq[3] = make_float2(0.5f * (acc[4] - acc[2]),  0.5f * (acc[5] - acc[3]));   // f1
        }
    }
    __syncthreads();

    // ---- Phase 5: T -> BA (reads BB = A1; BA's TMP is dead) ----
    {
        const float2 e0 = Sq[0], e1 = Sq[1], f0 = Sq[2], f1 = Sq[3];
        for (int idx = t; idx < 4096; idx += 1024) {
            int p = idx >> 6, q = idx & 63;
            int u = p ^ (p >> 1), v = q ^ (q >> 1);
            float2 c0, c1;
            pick_cc(p, q, e0, e1, f0, f1, c0, c1);
            float2 a  = BB[(u << 6) + v];
            float2 a2 = BB[((u ^ 48) << 6) + (v ^ 48)];
            BA[idx] = cadd(cmul(a, c0), cmul(a2, c1));
        }
    }
    __syncthreads();

    // ---- Phase 6: GEMM3 (quarter): U[i][j] = sum_k LA[i][k]*T[k][j] -> BB ----
    const int il = t >> 6;               // 0..15 local row
    const int i  = (rq << 4) + il;       // global row of this block's quarter
    const int j  = t & 63;
    {
        float2 u = make_float2(0, 0);
        #pragma unroll 16
        for (int k = 0; k < 64; ++k)
            u = cfmac(LAH[(k << 6) + i], BA[(k << 6) + j], u);  // conj(LAH)=LA
        __syncthreads();                 // T fully built; safe to overwrite BB
        BB[(il << 6) + j] = u;
    }
    __syncthreads();

    // ---- Phase 7: GEMM4 (quarter): R[i][j] = sum_k U[i][k]*LAH[k*64+j] -> out ----
    {
        float2 r = make_float2(0, 0);
        #pragma unroll 16
        for (int k = 0; k < 64; ++k)
            r = cfma(BB[(il << 6) + k], LAH[(k << 6) + j], r);
        if constexpr (OM == 0) {
            ((float*)outv)[(ev << 12) + (i << 6) + j] = r.x;          // real parts only
        } else if constexpr (OM == 1) {
            __hip_bfloat16* og = (__hip_bfloat16*)outv + (ev << 13) + (i << 7);
            og[2 * j]     = __float2bfloat16(r.x);
            og[2 * j + 1] = __float2bfloat16(r.y);
        } else {
            ((float2*)outv)[(ev << 12) + (i << 6) + j] = r;
        }
    }
}

extern "C" void kernel_launch(void* const* d_in, const int* in_sizes, int n_in,
                              void* d_out, int out_size, void* d_ws, size_t ws_size,
                              hipStream_t stream) {
    const float* A = (const float*)d_in[0];   // (2,64,64) f32
    const float* B = (const float*)d_in[1];   // (2,64,64) f32
    const float* w = (const float*)d_in[2];   // (72,) f32
    (void)in_sizes; (void)n_in; (void)d_ws; (void)ws_size;
    if (out_size == 16384)      qfused<0><<<16, 1024, 0, stream>>>(A, B, w, d_out);
    else if (out_size == 32768) qfused<1><<<16, 1024, 0, stream>>>(A, B, w, d_out);
    else                        qfused<2><<<16, 1024, 0, stream>>>(A, B, w, d_out);
}

// Round 6
// 81.300 us; speedup vs baseline: 1.2133x; 1.2133x over previous
//
#include <hip/hip_runtime.h>
#include <hip/hip_bf16.h>

// Qu mutual-information circuit: N_QUBITS=12, DIM=4096, SUB_DIM=64, 1 layer.
//
// Reduction (verified by passing benches r2/r3/r5):
//   L = LA (x) LB,  U = L P L,  Tr_B(U (X1(x)X2) U^H) = LA * T * LA^H
//   P GF(2)-linear => T[p,q] = A1[u,v]*W0(p0,q0) + A1[u^48,v^48]*W1(p0,q0),
//     u = p^(p>>1), v = q^(q>>1); coefficients from 4 scalars e0,e1,f0,f1 =
//     parity-split operator traces of the LB side (LB GEMMs eliminated).
//
// Structure (r6): two dispatches, fine-grained blocks (launch count is cheap;
// per-block critical path is the controllable cost — r5 lesson):
//   qk1: 36 blocks x 512 = 32 A1-octant blocks (4 inputs x 8 row-octants,
//        1 output/thread, wave-uniform LA-row broadcasts) + 4 trace blocks.
//   qk2: 32 blocks x 512 = (4 evolutions x 8 octants): T + LA*T*LA^H octant.
//   qfused fallback (passed r5) if ws too small.

#define W_MUL 0.6324555320336759f   // sqrt(2)/sqrt(5)

__device__ __forceinline__ float2 cmul(float2 a, float2 b) {
    return make_float2(a.x * b.x - a.y * b.y, a.x * b.y + a.y * b.x);
}
__device__ __forceinline__ float2 cadd(float2 a, float2 b) { return make_float2(a.x + b.x, a.y + b.y); }
__device__ __forceinline__ float2 csub(float2 a, float2 b) { return make_float2(a.x - b.x, a.y - b.y); }
__device__ __forceinline__ float2 conjc(float2 a) { return make_float2(a.x, -a.y); }
// c += a*b
__device__ __forceinline__ float2 cfma(float2 a, float2 b, float2 c) {
    c.x = fmaf(a.x, b.x, fmaf(-a.y, b.y, c.x));
    c.y = fmaf(a.x, b.y, fmaf( a.y, b.x, c.y));
    return c;
}
// c += conj(a)*b
__device__ __forceinline__ float2 cfmac(float2 a, float2 b, float2 c) {
    c.x = fmaf(a.x, b.x, fmaf( a.y, b.y, c.x));
    c.y = fmaf(a.x, b.y, fmaf(-a.y, b.x, c.y));
    return c;
}

// G_q = Rz(tz) @ Ry(ty) @ Rx(tx), 2x2 complex.
__device__ __forceinline__ void make_G(const float* w, int q, float2 G[2][2]) {
    float tx = w[q]      * (W_MUL * 0.5f);
    float ty = w[12 + q] * (W_MUL * 0.5f);
    float tz = w[24 + q] * (W_MUL * 0.5f);
    float cx, sx, cy, sy, cz, sz;
    sincosf(tx, &sx, &cx);
    sincosf(ty, &sy, &cy);
    sincosf(tz, &sz, &cz);
    float2 M00 = make_float2( cy * cx,  sy * sx);
    float2 M01 = make_float2(-sy * cx, -cy * sx);
    float2 M10 = make_float2( sy * cx, -cy * sx);
    float2 M11 = make_float2( cy * cx, -sy * sx);
    float2 ez  = make_float2(cz, -sz);
    float2 ezc = make_float2(cz,  sz);
    G[0][0] = cmul(ez,  M00);
    G[0][1] = cmul(ez,  M01);
    G[1][0] = cmul(ezc, M10);
    G[1][1] = cmul(ezc, M11);
}

// dst[k*64+i] = conj(L[i][k]) for L = kron(G[0..5]).
__device__ __forceinline__ void build_LH(const float2 G[6][2][2], float2* dst, int t, int nt) {
    for (int e = t; e < 4096; e += nt) {
        int i = e >> 6, j = e & 63;
        float2 p = G[0][(i >> 5) & 1][(j >> 5) & 1];
        p = cmul(p, G[1][(i >> 4) & 1][(j >> 4) & 1]);
        p = cmul(p, G[2][(i >> 3) & 1][(j >> 3) & 1]);
        p = cmul(p, G[3][(i >> 2) & 1][(j >> 2) & 1]);
        p = cmul(p, G[4][(i >> 1) & 1][(j >> 1) & 1]);
        p = cmul(p, G[5][(i     ) & 1][(j     ) & 1]);
        dst[j * 64 + i] = conjc(p);
    }
}

// 2x2 trace tables from G (qubits 6..11): zt[q] = Gq^H Z Gq; x6 = G6^H X G6; xz6 = G6^H (XZ) G6.
__device__ __forceinline__ void make_tables(const float2 G[6][2][2],
                                            float2 zt[6][2][2], float2 x6[2][2], float2 xz6[2][2]) {
    #pragma unroll
    for (int q = 0; q < 6; ++q)
        #pragma unroll
        for (int a = 0; a < 2; ++a)
            #pragma unroll
            for (int b = 0; b < 2; ++b) {
                float2 g0a = G[q][0][a], g0b = G[q][0][b];
                float2 g1a = G[q][1][a], g1b = G[q][1][b];
                zt[q][a][b] = csub(cmul(conjc(g0a), g0b), cmul(conjc(g1a), g1b));
                if (q == 0) {
                    x6[a][b]  = cadd(cmul(conjc(g0a), g1b), cmul(conjc(g1a), g0b));
                    xz6[a][b] = csub(cmul(conjc(g1a), g0b), cmul(conjc(g0a), g1b));
                }
            }
}

// Per-thread trace partials: acc = {tz.x,tz.y, txz.x,txz.y, tx.x,tx.y, t0}
__device__ __forceinline__ void trace_acc(const float* Xr, const float2 zt[6][2][2],
                                          const float2 x6[2][2], const float2 xz6[2][2],
                                          int t, int nt, float acc[7]) {
    for (int e = t; e < 4096; e += nt) {
        int r = e >> 6, c = e & 63;       // term X2[r][c] * K[c][r]
        float xv = Xr[e];
        float2 P = zt[1][(c >> 4) & 1][(r >> 4) & 1];
        P = cmul(P, zt[2][(c >> 3) & 1][(r >> 3) & 1]);
        P = cmul(P, zt[3][(c >> 2) & 1][(r >> 2) & 1]);
        P = cmul(P, zt[4][(c >> 1) & 1][(r >> 1) & 1]);
        P = cmul(P, zt[5][c & 1][r & 1]);
        float2 pz  = cmul(zt[0][c >> 5][r >> 5], P);
        float2 pxz = cmul(xz6[c >> 5][r >> 5], P);
        acc[0] = fmaf(pz.x,  xv, acc[0]); acc[1] = fmaf(pz.y,  xv, acc[1]);
        acc[2] = fmaf(pxz.x, xv, acc[2]); acc[3] = fmaf(pxz.y, xv, acc[3]);
        if ((c & 31) == (r & 31)) {
            float2 kx = x6[c >> 5][r >> 5];
            acc[4] = fmaf(kx.x, xv, acc[4]); acc[5] = fmaf(kx.y, xv, acc[5]);
            if (c == r) acc[6] += xv;
        }
    }
}

// Reduce acc[7] across the block; returns true on thread 0 with totals in acc.
template <int NT>
__device__ __forceinline__ bool reduce7(float acc[7], float (*red)[8], int t) {
    #pragma unroll
    for (int o = 32; o; o >>= 1)
        #pragma unroll
        for (int m = 0; m < 7; ++m) acc[m] += __shfl_down(acc[m], o);
    if ((t & 63) == 0)
        for (int m = 0; m < 7; ++m) red[t >> 6][m] = acc[m];
    __syncthreads();
    if (t == 0) {
        for (int m = 0; m < 7; ++m) {
            float s = 0.f;
            for (int wv = 0; wv < NT / 64; ++wv) s += red[wv][m];
            acc[m] = s;
        }
        return true;
    }
    return false;
}

// T coefficients by (p&1, q&1)
__device__ __forceinline__ void pick_cc(int p, int q, float2 e0, float2 e1, float2 f0, float2 f1,
                                        float2& c0, float2& c1) {
    if (p & 1) { if (q & 1) { c0 = e1; c1 = e0; } else { c0 = f1; c1 = f0; } }
    else       { if (q & 1) { c0 = f0; c1 = f1; } else { c0 = e0; c1 = e1; } }
}

// ---------------- qk1: A1 octants (blocks 0..31) + trace quads (blocks 32..35) ----------------
__global__ __launch_bounds__(512) void qk1(const float* __restrict__ A, const float* __restrict__ B,
                                           const float* __restrict__ w, float2* __restrict__ ws) {
    __shared__ float2 LAH[4096];
    __shared__ float  Xr[4096];
    __shared__ float2 TMP[512];
    __shared__ float2 G6[6][2][2];
    __shared__ float  red[8][8];

    const int bx = blockIdx.x;
    const int t  = threadIdx.x;

    if (bx < 32) {
        const int x   = bx >> 3;              // 0:A0 1:A1 2:B0 3:B1
        const int oct = bx & 7;
        const float* Xg = (x < 2) ? (A + x * 4096) : (B + (x - 2) * 4096);
        if (t < 6) make_G(w, t, G6[t]);
        __syncthreads();
        build_LH(G6, LAH, t, 512);
        for (int e = t; e < 4096; e += 512) Xr[e] = Xg[e];
        __syncthreads();

        const int il = t >> 6;                // wave id = local row 0..7
        const int j  = t & 63;                // lane = column
        const int i  = (oct << 3) + il;       // global A1 row

        // GEMM1: TMP[il][j] = sum_k conj(LAH[k*64+i]) * X[k][j]  (LA row broadcast, X real)
        float ax = 0.f, ay = 0.f;
        #pragma unroll 16
        for (int k = 0; k < 64; ++k) {
            float2 la = LAH[(k << 6) + i];    // wave-uniform -> LDS broadcast
            float  xv = Xr[(k << 6) + j];
            ax = fmaf(la.x, xv, ax);
            ay = fmaf(-la.y, xv, ay);
        }
        TMP[(il << 6) + j] = make_float2(ax, ay);
        __syncthreads();

        // GEMM2: A1[i][j] = sum_k TMP[il][k] * LAH[k*64+j]
        float2 c = make_float2(0.f, 0.f);
        #pragma unroll 16
        for (int k = 0; k < 64; ++k)
            c = cfma(TMP[(il << 6) + k], LAH[(k << 6) + j], c);   // TMP broadcast
        ws[(x << 12) + (i << 6) + j] = c;
    } else {
        const int x = bx - 32;
        const float* Xg = (x < 2) ? (A + x * 4096) : (B + (x - 2) * 4096);
        if (t < 6) make_G(w, 6 + t, G6[t]);
        for (int e = t; e < 4096; e += 512) Xr[e] = Xg[e];
        __syncthreads();
        float2 zt[6][2][2], x6[2][2], xz6[2][2];
        make_tables(G6, zt, x6, xz6);
        float acc[7] = {0, 0, 0, 0, 0, 0, 0};
        trace_acc(Xr, zt, x6, xz6, t, 512, acc);
        if (reduce7<512>(acc, red, t)) {
            float2* S = ws + 16384 + (x << 2);
            S[0] = make_float2(0.5f * (acc[6] + acc[0]),  0.5f * acc[1]);              // e0
            S[1] = make_float2(0.5f * (acc[6] - acc[0]), -0.5f * acc[1]);              // e1
            S[2] = make_float2(0.5f * (acc[4] + acc[2]),  0.5f * (acc[5] + acc[3]));   // f0
            S[3] = make_float2(0.5f * (acc[4] - acc[2]),  0.5f * (acc[5] - acc[3]));   // f1
        }
    }
}

// ---------------- qk2: (evolution x octant): T, octant of R = LA*T*LA^H -> out ----------------
template <int OM>
__global__ __launch_bounds__(512) void qk2(const float* __restrict__ w, const float2* __restrict__ ws,
                                           void* __restrict__ outv) {
    __shared__ float2 LAH[4096];
    __shared__ float2 A1s[4096];
    __shared__ float2 Ts[4096];
    __shared__ float2 Us[512];
    __shared__ float2 G6[6][2][2];

    const int bx = blockIdx.x;
    const int ev = bx >> 3, oct = bx & 7;
    const int order = ev >> 1, b = ev & 1;
    const int x1 = order ? 2 + b : b;         // LA-side input
    const int x2 = order ? b : 2 + b;         // LB-side (traced) input
    const int t = threadIdx.x;

    if (t < 6) make_G(w, t, G6[t]);
    __syncthreads();
    build_LH(G6, LAH, t, 512);
    for (int e = t; e < 4096; e += 512) A1s[e] = ws[(x1 << 12) + e];
    __syncthreads();

    const float2 e0 = ws[16384 + (x2 << 2) + 0];
    const float2 e1 = ws[16384 + (x2 << 2) + 1];
    const float2 f0 = ws[16384 + (x2 << 2) + 2];
    const float2 f1 = ws[16384 + (x2 << 2) + 3];

    // T: 8 elems/thread; p wave-uniform per chunk, v = Gray(lane) bijective.
    for (int idx = t; idx < 4096; idx += 512) {
        int p = idx >> 6, q = idx & 63;
        int u = p ^ (p >> 1), v = q ^ (q >> 1);
        float2 c0, c1;
        pick_cc(p, q, e0, e1, f0, f1, c0, c1);
        float2 a  = A1s[(u << 6) + v];
        float2 a2 = A1s[((u ^ 48) << 6) + (v ^ 48)];
        Ts[idx] = cadd(cmul(a, c0), cmul(a2, c1));
    }
    __syncthreads();

    const int il = t >> 6;                   // wave id = local row
    const int j  = t & 63;
    const int i  = (oct << 3) + il;          // global output row

    // GEMM3: U[i][j] = sum_k LA[i][k] * T[k][j]   (LA row broadcast)
    float2 u = make_float2(0.f, 0.f);
    #pragma unroll 16
    for (int k = 0; k < 64; ++k)
        u = cfmac(LAH[(k << 6) + i], Ts[(k << 6) + j], u);   // conj(LAH) = LA
    Us[(il << 6) + j] = u;
    __syncthreads();

    // GEMM4: R[i][j] = sum_k U[i][k] * LAH[k*64+j]   (U row broadcast)
    float2 r = make_float2(0.f, 0.f);
    #pragma unroll 16
    for (int k = 0; k < 64; ++k)
        r = cfma(Us[(il << 6) + k], LAH[(k << 6) + j], r);

    if constexpr (OM == 0) {
        ((float*)outv)[(ev << 12) + (i << 6) + j] = r.x;             // real parts only
    } else if constexpr (OM == 1) {
        __hip_bfloat16* og = (__hip_bfloat16*)outv + (ev << 13) + (i << 7);
        og[2 * j]     = __float2bfloat16(r.x);
        og[2 * j + 1] = __float2bfloat16(r.y);
    } else {
        ((float2*)outv)[(ev << 12) + (i << 6) + j] = r;
    }
}

// ---------------- Fallback: r5 fused kernel (passed), used only if ws too small ----------------
template <int OM>
__global__ __launch_bounds__(1024) void qfused(const float* __restrict__ A, const float* __restrict__ B,
                                               const float* __restrict__ w, void* __restrict__ outv) {
    __shared__ float2 LAH[4096];
    __shared__ float  Xr[4096];
    __shared__ float2 BA[4096];
    __shared__ float2 BB[4096];
    __shared__ float2 G6[6][2][2];
    __shared__ float  red[16][8];
    __shared__ float2 Sq[4];

    const int bx = blockIdx.x;
    const int ev = bx >> 2, rq = bx & 3;
    const int order = ev >> 1, b = ev & 1;
    const int t = threadIdx.x;
    const float* X1g = (order ? B : A) + b * 4096;
    const float* X2g = (order ? A : B) + b * 4096;

    if (t < 6) make_G(w, t, G6[t]);
    __syncthreads();
    build_LH(G6, LAH, t, 1024);
    for (int e = t; e < 4096; e += 1024) Xr[e] = X1g[e];
    __syncthreads();

    const int tr = t >> 5, tc = t & 31;
    const int i0 = tr, i1 = tr + 32;
    {
        float2 a00 = {0,0}, a01 = {0,0}, a10 = {0,0}, a11 = {0,0};
        #pragma unroll 16
        for (int k = 0; k < 64; ++k) {
            float2 la0 = LAH[(k << 6) + i0], la1 = LAH[(k << 6) + i1];
            float x0 = Xr[(k << 6) + tc], x1 = Xr[(k << 6) + tc + 32];
            a00.x = fmaf(la0.x, x0, a00.x); a00.y = fmaf(-la0.y, x0, a00.y);
            a01.x = fmaf(la0.x, x1, a01.x); a01.y = fmaf(-la0.y, x1, a01.y);
            a10.x = fmaf(la1.x, x0, a10.x); a10.y = fmaf(-la1.y, x0, a10.y);
            a11.x = fmaf(la1.x, x1, a11.x); a11.y = fmaf(-la1.y, x1, a11.y);
        }
        BA[(i0 << 6) + tc] = a00; BA[(i0 << 6) + tc + 32] = a01;
        BA[(i1 << 6) + tc] = a10; BA[(i1 << 6) + tc + 32] = a11;
    }
    __syncthreads();
    {
        float2 a00 = {0,0}, a01 = {0,0}, a10 = {0,0}, a11 = {0,0};
        #pragma unroll 16
        for (int k = 0; k < 64; ++k) {
            float2 t0 = BA[(i0 << 6) + k], t1 = BA[(i1 << 6) + k];
            float2 l0 = LAH[(k << 6) + tc], l1 = LAH[(k << 6) + tc + 32];
            a00 = cfma(t0, l0, a00); a01 = cfma(t0, l1, a01);
            a10 = cfma(t1, l0, a10); a11 = cfma(t1, l1, a11);
        }
        BB[(i0 << 6) + tc] = a00; BB[(i0 << 6) + tc + 32] = a01;
        BB[(i1 << 6) + tc] = a10; BB[(i1 << 6) + tc + 32] = a11;
    }
    __syncthreads();
    for (int e = t; e < 4096; e += 1024) Xr[e] = X2g[e];
    if (t < 6) make_G(w, 6 + t, G6[t]);
    __syncthreads();
    {
        float2 zt[6][2][2], x6[2][2], xz6[2][2];
        make_tables(G6, zt, x6, xz6);
        float acc[7] = {0, 0, 0, 0, 0, 0, 0};
        trace_acc(Xr, zt, x6, xz6, t, 1024, acc);
        if (reduce7<1024>(acc, red, t)) {
            Sq[0] = make_float2(0.5f * (acc[6] + acc[0]),  0.5f * acc[1]);
            Sq[1] = make_float2(0.5f * (acc[6] - acc[0]), -0.5f * acc[1]);
            Sq[2] = make_float2(0.5f * (acc[4] + acc[2]),  0.5f * (acc[5] + acc[3]));
            Sq[3] = make_float2(0.5f * (acc[4] - acc[2]),  0.5f * (acc[5] - acc[3]));
        }
    }
    __syncthreads();
    {
        const float2 e0 = Sq[0], e1 = Sq[1], f0 = Sq[2], f1 = Sq[3];
        for (int idx = t; idx < 4096; idx += 1024) {
            int p = idx >> 6, q = idx & 63;
            int u = p ^ (p >> 1), v = q ^ (q >> 1);
            float2 c0, c1;
            pick_cc(p, q, e0, e1, f0, f1, c0, c1);
            float2 a  = BB[(u << 6) + v];
            float2 a2 = BB[((u ^ 48) << 6) + (v ^ 48)];
            BA[idx] = cadd(cmul(a, c0), cmul(a2, c1));
        }
    }
    __syncthreads();
    const int il = t >> 6;
    const int i  = (rq << 4) + il;
    const int j  = t & 63;
    {
        float2 u = make_float2(0, 0);
        #pragma unroll 16
        for (int k = 0; k < 64; ++k)
            u = cfmac(LAH[(k << 6) + i], BA[(k << 6) + j], u);
        __syncthreads();
        BB[(il << 6) + j] = u;
    }
    __syncthreads();
    {
        float2 r = make_float2(0, 0);
        #pragma unroll 16
        for (int k = 0; k < 64; ++k)
            r = cfma(BB[(il << 6) + k], LAH[(k << 6) + j], r);
        if constexpr (OM == 0) {
            ((float*)outv)[(ev << 12) + (i << 6) + j] = r.x;
        } else if constexpr (OM == 1) {
            __hip_bfloat16* og = (__hip_bfloat16*)outv + (ev << 13) + (i << 7);
            og[2 * j]     = __float2bfloat16(r.x);
            og[2 * j + 1] = __float2bfloat16(r.y);
        } else {
            ((float2*)outv)[(ev << 12) + (i << 6) + j] = r;
        }
    }
}

extern "C" void kernel_launch(void* const* d_in, const int* in_sizes, int n_in,
                              void* d_out, int out_size, void* d_ws, size_t ws_size,
                              hipStream_t stream) {
    const float* A = (const float*)d_in[0];   // (2,64,64) f32
    const float* B = (const float*)d_in[1];   // (2,64,64) f32
    const float* w = (const float*)d_in[2];   // (72,) f32
    (void)in_sizes; (void)n_in;
    const bool two = (ws_size >= 16400u * sizeof(float2));   // 131,200 B
    if (two) {
        qk1<<<36, 512, 0, stream>>>(A, B, w, (float2*)d_ws);
        if (out_size == 16384)      qk2<0><<<32, 512, 0, stream>>>(w, (const float2*)d_ws, d_out);
        else if (out_size == 32768) qk2<1><<<32, 512, 0, stream>>>(w, (const float2*)d_ws, d_out);
        else                        qk2<2><<<32, 512, 0, stream>>>(w, (const float2*)d_ws, d_out);
    } else {
        if (out_size == 16384)      qfused<0><<<16, 1024, 0, stream>>>(A, B, w, d_out);
        else if (out_size == 32768) qfused<1><<<16, 1024, 0, stream>>>(A, B, w, d_out);
        else                        qfused<2><<<16, 1024, 0, stream>>>(A, B, w, d_out);
    }
}